// Round 17
// baseline (117.783 us; speedup 1.0000x reference)
//
#include <hip/hip_runtime.h>
#include <hip/hip_bf16.h>

#define BS   8
#define NREL 16
#define NN   512
#define EMB  256

typedef float f32x4 __attribute__((ext_vector_type(4)));
typedef short s16x8 __attribute__((ext_vector_type(8)));

// f32 -> bf16 bits, round-to-nearest-even
__device__ __forceinline__ unsigned short f2bf_bits(float f) {
    union { float f; unsigned u; } v; v.f = f;
    unsigned r = (v.u + 0x7FFFu + ((v.u >> 16) & 1u)) >> 16;
    return (unsigned short)r;
}

__device__ __forceinline__ float bf2f(unsigned short u) {
    union { unsigned u; float f; } v; v.u = ((unsigned)u) << 16;
    return v.f;
}

// hw cvt path (compiler emits v_cvt_pk_bf16_f32 when paired)
__device__ __forceinline__ unsigned short f2bf_hw(float f) {
    union { __hip_bfloat16 h; unsigned short u; } v;
    v.h = __float2bfloat16(f);
    return v.u;
}

// ---------------------------------------------------------------------------
// K0: fused prep.  bid < 1088: transpose W_r + W_0 -> wT[17][h][d] bf16.
//     bid >= 1088: convert F f32 -> Fbf bf16 (512 blocks x 2048 elems).
// ---------------------------------------------------------------------------
__global__ __launch_bounds__(256) void k0_prep(
        const float* __restrict__ Wr, const float* __restrict__ W0,
        const float* __restrict__ F,
        unsigned short* __restrict__ wT, unsigned short* __restrict__ Fbf) {
    int bid = blockIdx.x;
    if (bid < 1088) {
        __shared__ float tile[32][33];
        int rel = bid / 64;          // 0..16
        int t   = bid % 64;
        int d0  = (t & 7) * 32;
        int h0  = (t >> 3) * 32;
        int tx  = threadIdx.x & 31;
        int ty  = threadIdx.x >> 5;  // 0..7
        const float* src = (rel < NREL) ? (Wr + rel * (EMB * EMB)) : W0;
#pragma unroll
        for (int k = 0; k < 4; ++k) {
            int d = d0 + ty + k * 8;
            tile[ty + k * 8][tx] = src[d * EMB + h0 + tx];
        }
        __syncthreads();
#pragma unroll
        for (int k = 0; k < 4; ++k) {
            int h = h0 + ty + k * 8;
            wT[(rel * EMB + h) * EMB + d0 + tx] = f2bf_bits(tile[tx][ty + k * 8]);
        }
    } else {
        long i = ((long)(bid - 1088) * 256 + threadIdx.x) * 8;
        f32x4 x0 = *(const f32x4*)(F + i);
        f32x4 x1 = *(const f32x4*)(F + i + 4);
        s16x8 v;
        v[0] = (short)f2bf_bits(x0[0]); v[1] = (short)f2bf_bits(x0[1]);
        v[2] = (short)f2bf_bits(x0[2]); v[3] = (short)f2bf_bits(x0[3]);
        v[4] = (short)f2bf_bits(x1[0]); v[5] = (short)f2bf_bits(x1[1]);
        v[6] = (short)f2bf_bits(x1[2]); v[7] = (short)f2bf_bits(x1[3]);
        *(s16x8*)(Fbf + i) = v;
    }
}

// ---------------------------------------------------------------------------
// K1: FW[b][rel][m][h] = sum_d F[b][m][d] * W[rel][d][h]
//   D[h][m] = wT(A) x Fbf(B), MFMA 16x16x32 bf16; distance-1 fragment dbuf.
//   rel<16  -> FW fragment-major: [(b*16+rel)*64 + m/8][h][m%8] bf16
//   rel==16 -> F2b bf16 row-major [b][n][h]
// ---------------------------------------------------------------------------
__global__ __launch_bounds__(256) void k1_fw(
        const unsigned short* __restrict__ Fbf, const unsigned short* __restrict__ wT,
        unsigned short* __restrict__ FW, unsigned short* __restrict__ F2b) {
    int bid = blockIdx.x;
    int b   = bid & 7;
    int q   = bid >> 3;          // 0..135
    int rel = q % 17;
    int mt  = q / 17;            // 0..7
    int tid = threadIdx.x;
    int w   = tid >> 6;          // 0..3
    int l   = tid & 63;
    int lg  = l >> 4;            // 0..3
    int lr  = l & 15;

    int h0 = w * 64;             // wave's 64 h-rows (M-dim)
    int m0 = mt * 64;            // block's 64 m-cols (N-dim)

    const unsigned short* wt = wT + rel * (EMB * EMB) + lg * 8;
    const unsigned short* Fb = Fbf + (long)b * (NN * EMB) + lg * 8;

    f32x4 acc[4][4];
#pragma unroll
    for (int i = 0; i < 4; ++i)
#pragma unroll
        for (int j = 0; j < 4; ++j) acc[i][j] = (f32x4){0.f, 0.f, 0.f, 0.f};

    s16x8 afr[2][4], bfr[2][4];
    // preload kk=0
#pragma unroll
    for (int hi = 0; hi < 4; ++hi)
        afr[0][hi] = *(const s16x8*)(wt + (h0 + hi * 16 + lr) * EMB);
#pragma unroll
    for (int bi = 0; bi < 4; ++bi)
        bfr[0][bi] = *(const s16x8*)(Fb + (m0 + bi * 16 + lr) * EMB);

#pragma unroll
    for (int kk = 0; kk < 8; ++kk) {
        int cur = kk & 1, nxt = cur ^ 1;
        if (kk < 7) {
            int ko = (kk + 1) * 32;
#pragma unroll
            for (int hi = 0; hi < 4; ++hi)
                afr[nxt][hi] = *(const s16x8*)(wt + (h0 + hi * 16 + lr) * EMB + ko);
#pragma unroll
            for (int bi = 0; bi < 4; ++bi)
                bfr[nxt][bi] = *(const s16x8*)(Fb + (m0 + bi * 16 + lr) * EMB + ko);
        }
#pragma unroll
        for (int hi = 0; hi < 4; ++hi)
#pragma unroll
            for (int bi = 0; bi < 4; ++bi)
                acc[hi][bi] = __builtin_amdgcn_mfma_f32_16x16x32_bf16(
                    afr[cur][hi], bfr[cur][bi], acc[hi][bi], 0, 0, 0);
    }

    // Epilogue: D rows = h, cols = m.  C layout: col = lane&15, row = (lane>>4)*4+j
#pragma unroll
    for (int hi = 0; hi < 4; ++hi) {
#pragma unroll
        for (int bi = 0; bi < 4; ++bi) {
            int m  = m0 + bi * 16 + lr;
            int kg = m >> 3, ko = m & 7;
#pragma unroll
            for (int j = 0; j < 4; ++j) {
                int h = h0 + hi * 16 + lg * 4 + j;
                if (rel < NREL)
                    FW[(long)((b * 16 + rel) * 64 + kg) * 2048 + h * 8 + ko] =
                        f2bf_bits(acc[hi][bi][j]);
                else
                    F2b[((long)b * NN + m) * EMB + h] = f2bf_bits(acc[hi][bi][j]);
            }
        }
    }
}

// ---------------------------------------------------------------------------
// K2: part[rg][b][n][h] (bf16) = sum_{r in rg(2 rels)} adj[b][r] @ FW[b][r]
//   grid 256 = 8b (XCD-pinned) x 4nt(128 rows) x 8rg(2 rels), 1 block/CU
//   block 512 thr = 8 waves = 4 wr(32-row groups) x 2 wc(K-slice parity).
//   Wave: 32 rows x 256 cols, acc[2][16].
//   DEEP-PREFETCH reg-staged pipeline (r16 sync structure, deeper rings):
//     adjacency: 4-slot ring, 3 slices in flight (~2000+ cyc latency cover)
//     FW: 2-pair reg ring, 2 iterations in flight
//   Loads remain in flight ACROSS barriers (lgkm-only barrier discipline,
//   no vmcnt(0) anywhere in the loop; compiler inserts counted vmcnt waits
//   at first use).  Epilogue cross-parity LDS reduce, bf16 partial store.
// ---------------------------------------------------------------------------
__global__ __launch_bounds__(512, 2) void k2_main(
        const float* __restrict__ adj, const unsigned short* __restrict__ FW,
        unsigned short* __restrict__ part) {
    __shared__ unsigned short Blds[2][16384];   // [buf][pair: 2 slices x 8192 sh] 64KB
    int bid = blockIdx.x;
    int b   = bid & 7;
    int t   = bid >> 3;          // 0..31
    int nt  = t & 3;
    int rg  = t >> 2;            // 0..7
    int tid = threadIdx.x;
    int w   = tid >> 6;          // 0..7
    int l   = tid & 63;
    int lg  = l >> 4, lr = l & 15;
    int wr  = w >> 1;            // 0..3 : 32-row group
    int wc  = w & 1;             // 0..1 : K-slice parity

    int nrow = nt * 128 + wr * 32;    // wave's 32 output rows

    f32x4 acc0[16], acc1[16];
#pragma unroll
    for (int i = 0; i < 16; ++i) {
        acc0[i] = (f32x4){0.f, 0.f, 0.f, 0.f};
        acc1[i] = (f32x4){0.f, 0.f, 0.f, 0.f};
    }

    // adjacency: rows nrow+lr and nrow+16+lr, 32-float chunk at lg*8
    const float* adjb0 =
        adj + (((long)(b * 16 + rg * 2)) * NN + nrow + lr) * NN + lg * 8;
    const float* adjb1 = adjb0 + 16 * NN;
    const unsigned short* fwb = FW + (long)(b * 16 + rg * 2) * 131072;

    // FW staging ring: slot p&1 holds pair p (4 x 16B lane-contiguous)
    s16x8 fwr[2][4];
    // adjacency ring: slot d&3 holds slice 2d+wc (per parity)
    f32x4 ax[4][2], ay[4][2];

#define POFF(p) ((long)((p) >> 3) * 131072 + ((p) & 7) * 16384)
#define AOFF(sl) ((long)((sl) >> 4) * (NN * NN) + ((sl) & 15) * 32)

    // ---- prologue ----
    {   // pair 0 -> regs slot0 -> LDS buf0
        const unsigned short* s = fwb + POFF(0) + tid * 8;
#pragma unroll
        for (int c = 0; c < 4; ++c) fwr[0][c] = *(const s16x8*)(s + c * 4096);
#pragma unroll
        for (int c = 0; c < 4; ++c)
            *(s16x8*)(&Blds[0][c * 4096 + tid * 8]) = fwr[0][c];
    }
    // adjacency slices d=0,1,2 (slice 2d+wc) -> slots 0,1,2
#pragma unroll
    for (int d = 0; d < 3; ++d) {
        long ao = AOFF(2 * d + wc);
        const float* p0 = adjb0 + ao;
        const float* p1 = adjb1 + ao;
        ax[d][0] = *(const f32x4*)p0; ay[d][0] = *(const f32x4*)(p0 + 4);
        ax[d][1] = *(const f32x4*)p1; ay[d][1] = *(const f32x4*)(p1 + 4);
    }
    {   // pair 1 -> slot1, pair 2 -> slot0 (slot0 freed by the ds_write above)
        const unsigned short* s1 = fwb + POFF(1) + tid * 8;
#pragma unroll
        for (int c = 0; c < 4; ++c) fwr[1][c] = *(const s16x8*)(s1 + c * 4096);
        const unsigned short* s2 = fwb + POFF(2) + tid * 8;
#pragma unroll
        for (int c = 0; c < 4; ++c) fwr[0][c] = *(const s16x8*)(s2 + c * 4096);
    }
    asm volatile("s_waitcnt lgkmcnt(0)" ::: "memory");
    __builtin_amdgcn_sched_barrier(0);
    __builtin_amdgcn_s_barrier();
    asm volatile("" ::: "memory");

#pragma unroll
    for (int i = 0; i < 16; ++i) {
        // 1. issue adjacency slice 2(i+3)+wc into slot (i+3)&3 (3-deep)
        if (i + 3 < 16) {
            long ao = AOFF(2 * (i + 3) + wc);
            const float* p0 = adjb0 + ao;
            const float* p1 = adjb1 + ao;
            ax[(i + 3) & 3][0] = *(const f32x4*)p0;
            ay[(i + 3) & 3][0] = *(const f32x4*)(p0 + 4);
            ax[(i + 3) & 3][1] = *(const f32x4*)p1;
            ay[(i + 3) & 3][1] = *(const f32x4*)(p1 + 4);
        }

        // 2. compute slice 2i+wc from Blds[i&1] (parity half wc)
        f32x4 x00 = ax[i & 3][0], x01 = ay[i & 3][0];
        f32x4 x10 = ax[i & 3][1], x11 = ay[i & 3][1];
        s16x8 a0, a1;
        a0[0] = (short)f2bf_hw(x00[0]); a0[1] = (short)f2bf_hw(x00[1]);
        a0[2] = (short)f2bf_hw(x00[2]); a0[3] = (short)f2bf_hw(x00[3]);
        a0[4] = (short)f2bf_hw(x01[0]); a0[5] = (short)f2bf_hw(x01[1]);
        a0[6] = (short)f2bf_hw(x01[2]); a0[7] = (short)f2bf_hw(x01[3]);
        a1[0] = (short)f2bf_hw(x10[0]); a1[1] = (short)f2bf_hw(x10[1]);
        a1[2] = (short)f2bf_hw(x10[2]); a1[3] = (short)f2bf_hw(x10[3]);
        a1[4] = (short)f2bf_hw(x11[0]); a1[5] = (short)f2bf_hw(x11[1]);
        a1[6] = (short)f2bf_hw(x11[2]); a1[7] = (short)f2bf_hw(x11[3]);

        const unsigned short* bl = &Blds[i & 1][wc * 8192 + lg * 2048];
#pragma unroll
        for (int f = 0; f < 16; ++f) {
            s16x8 bf = *(const s16x8*)(bl + (f * 16 + lr) * 8);
            acc0[f] = __builtin_amdgcn_mfma_f32_16x16x32_bf16(a0, bf, acc0[f], 0, 0, 0);
            acc1[f] = __builtin_amdgcn_mfma_f32_16x16x32_bf16(a1, bf, acc1[f], 0, 0, 0);
        }
        asm volatile("" ::: "memory");   // ds_reads above, ds_writes below

        // 3. ds_write pair i+1 from fwr[(i+1)&1]; reload that slot with pair i+3
        if (i + 1 < 16) {
            unsigned short* dst = &Blds[(i + 1) & 1][tid * 8];
#pragma unroll
            for (int c = 0; c < 4; ++c)
                *(s16x8*)(dst + c * 4096) = fwr[(i + 1) & 1][c];
            if (i + 3 < 16) {
                const unsigned short* s = fwb + POFF(i + 3) + tid * 8;
#pragma unroll
                for (int c = 0; c < 4; ++c)
                    fwr[(i + 1) & 1][c] = *(const s16x8*)(s + c * 4096);
            }
            asm volatile("s_waitcnt lgkmcnt(0)" ::: "memory");
            __builtin_amdgcn_sched_barrier(0);
            __builtin_amdgcn_s_barrier();
            asm volatile("" ::: "memory");
        }
    }
#undef POFF
#undef AOFF

    // ---- cross-wc reduce via LDS, 2 chunks (g = row-group), bf16 store
    float* lf = (float*)Blds;          // 16384 floats = 64KB
    unsigned short* pp = part + ((long)rg * BS + b) * (NN * EMB);
#pragma unroll
    for (int g = 0; g < 2; ++g) {
        __syncthreads();
        if (wc == 1) {
#pragma unroll
            for (int f = 0; f < 16; ++f)
#pragma unroll
                for (int j = 0; j < 4; ++j)
                    lf[wr * 4096 + (f * 4 + j) * 64 + l] =
                        g ? acc1[f][j] : acc0[f][j];
        }
        __syncthreads();
        if (wc == 0) {
#pragma unroll
            for (int f = 0; f < 16; ++f) {
                int h = f * 16 + lr;
#pragma unroll
                for (int j = 0; j < 4; ++j) {
                    int n = nrow + g * 16 + lg * 4 + j;
                    float v = (g ? acc1[f][j] : acc0[f][j]) +
                              lf[wr * 4096 + (f * 4 + j) * 64 + l];
                    pp[(long)n * EMB + h] = f2bf_bits(v);
                }
            }
        }
    }
}

// ---------------------------------------------------------------------------
// K3: out = relu(sum over 8 bf16 part slices + F2b), 8 elems/thread
// ---------------------------------------------------------------------------
__global__ __launch_bounds__(256) void k3_reduce(
        const unsigned short* __restrict__ part,
        const unsigned short* __restrict__ F2b, float* __restrict__ out) {
    const long PS = (long)BS * NN * EMB;   // elements per rg slice
    long i = ((long)blockIdx.x * 256 + threadIdx.x) * 8;
    float s[8];
    {
        s16x8 v = *(const s16x8*)(F2b + i);
#pragma unroll
        for (int j = 0; j < 8; ++j) s[j] = bf2f((unsigned short)v[j]);
    }
#pragma unroll
    for (int rg = 0; rg < 8; ++rg) {
        s16x8 v = *(const s16x8*)(part + (long)rg * PS + i);
#pragma unroll
        for (int j = 0; j < 8; ++j) s[j] += bf2f((unsigned short)v[j]);
    }
    f32x4 r0, r1;
#pragma unroll
    for (int j = 0; j < 4; ++j) {
        r0[j] = s[j] > 0.f ? s[j] : 0.f;
        r1[j] = s[j + 4] > 0.f ? s[j + 4] : 0.f;
    }
    *(f32x4*)(out + i) = r0;
    *(f32x4*)(out + i + 4) = r1;
}

// ---------------------------------------------------------------------------
extern "C" void kernel_launch(void* const* d_in, const int* in_sizes, int n_in,
                              void* d_out, int out_size, void* d_ws, size_t ws_size,
                              hipStream_t stream) {
    const float* F   = (const float*)d_in[0];   // [8][512][256]
    const float* adj = (const float*)d_in[1];   // [8][16][512][512]
    const float* Wr  = (const float*)d_in[2];   // [16][256][256]
    const float* W0  = (const float*)d_in[3];   // [256][256]
    float* out = (float*)d_out;                 // [8][512][256]

    unsigned short* wT   = (unsigned short*)d_ws;            // 17*256*256 bf16
    unsigned short* Fbf  = wT + 17 * 256 * 256;              // 8*512*256 bf16
    unsigned short* FW   = Fbf + (long)8 * 512 * 256;        // 8*16*64*2048 bf16
    unsigned short* F2b  = FW + (long)8 * 16 * 64 * 2048;    // 8*512*256 bf16
    unsigned short* part = F2b + (long)8 * 512 * 256;        // 8 slices bf16

    k0_prep<<<1600, 256, 0, stream>>>(Wr, W0, F, wT, Fbf);
    k1_fw<<<1088, 256, 0, stream>>>(Fbf, wT, FW, F2b);
    k2_main<<<256, 512, 0, stream>>>(adj, FW, part);
    k3_reduce<<<512, 256, 0, stream>>>(part, F2b, out);
}

// Round 18
// 107.497 us; speedup vs baseline: 1.0957x; 1.0957x over previous
//
#include <hip/hip_runtime.h>
#include <hip/hip_bf16.h>

#define BS   8
#define NREL 16
#define NN   512
#define EMB  256

typedef float f32x4 __attribute__((ext_vector_type(4)));
typedef short s16x8 __attribute__((ext_vector_type(8)));

// f32 -> bf16 bits, round-to-nearest-even
__device__ __forceinline__ unsigned short f2bf_bits(float f) {
    union { float f; unsigned u; } v; v.f = f;
    unsigned r = (v.u + 0x7FFFu + ((v.u >> 16) & 1u)) >> 16;
    return (unsigned short)r;
}

__device__ __forceinline__ float bf2f(unsigned short u) {
    union { unsigned u; float f; } v; v.u = ((unsigned)u) << 16;
    return v.f;
}

// hw cvt path (compiler emits v_cvt_pk_bf16_f32 when paired)
__device__ __forceinline__ unsigned short f2bf_hw(float f) {
    union { __hip_bfloat16 h; unsigned short u; } v;
    v.h = __float2bfloat16(f);
    return v.u;
}

// ---------------------------------------------------------------------------
// K0: fused prep.  bid < 1088: transpose W_r + W_0 -> wT[17][h][d] bf16.
//     bid >= 1088: convert F f32 -> Fbf bf16 (512 blocks x 2048 elems).
// ---------------------------------------------------------------------------
__global__ __launch_bounds__(256) void k0_prep(
        const float* __restrict__ Wr, const float* __restrict__ W0,
        const float* __restrict__ F,
        unsigned short* __restrict__ wT, unsigned short* __restrict__ Fbf) {
    int bid = blockIdx.x;
    if (bid < 1088) {
        __shared__ float tile[32][33];
        int rel = bid / 64;          // 0..16
        int t   = bid % 64;
        int d0  = (t & 7) * 32;
        int h0  = (t >> 3) * 32;
        int tx  = threadIdx.x & 31;
        int ty  = threadIdx.x >> 5;  // 0..7
        const float* src = (rel < NREL) ? (Wr + rel * (EMB * EMB)) : W0;
#pragma unroll
        for (int k = 0; k < 4; ++k) {
            int d = d0 + ty + k * 8;
            tile[ty + k * 8][tx] = src[d * EMB + h0 + tx];
        }
        __syncthreads();
#pragma unroll
        for (int k = 0; k < 4; ++k) {
            int h = h0 + ty + k * 8;
            wT[(rel * EMB + h) * EMB + d0 + tx] = f2bf_bits(tile[tx][ty + k * 8]);
        }
    } else {
        long i = ((long)(bid - 1088) * 256 + threadIdx.x) * 8;
        f32x4 x0 = *(const f32x4*)(F + i);
        f32x4 x1 = *(const f32x4*)(F + i + 4);
        s16x8 v;
        v[0] = (short)f2bf_bits(x0[0]); v[1] = (short)f2bf_bits(x0[1]);
        v[2] = (short)f2bf_bits(x0[2]); v[3] = (short)f2bf_bits(x0[3]);
        v[4] = (short)f2bf_bits(x1[0]); v[5] = (short)f2bf_bits(x1[1]);
        v[6] = (short)f2bf_bits(x1[2]); v[7] = (short)f2bf_bits(x1[3]);
        *(s16x8*)(Fbf + i) = v;
    }
}

// ---------------------------------------------------------------------------
// K1: FW[b][rel][m][h] = sum_d F[b][m][d] * W[rel][d][h]
//   D[h][m] = wT(A) x Fbf(B), MFMA 16x16x32 bf16; distance-1 fragment dbuf.
//   rel<16  -> FW fragment-major: [(b*16+rel)*64 + m/8][h][m%8] bf16
//   rel==16 -> F2b bf16 row-major [b][n][h]
// ---------------------------------------------------------------------------
__global__ __launch_bounds__(256) void k1_fw(
        const unsigned short* __restrict__ Fbf, const unsigned short* __restrict__ wT,
        unsigned short* __restrict__ FW, unsigned short* __restrict__ F2b) {
    int bid = blockIdx.x;
    int b   = bid & 7;
    int q   = bid >> 3;          // 0..135
    int rel = q % 17;
    int mt  = q / 17;            // 0..7
    int tid = threadIdx.x;
    int w   = tid >> 6;          // 0..3
    int l   = tid & 63;
    int lg  = l >> 4;            // 0..3
    int lr  = l & 15;

    int h0 = w * 64;             // wave's 64 h-rows (M-dim)
    int m0 = mt * 64;            // block's 64 m-cols (N-dim)

    const unsigned short* wt = wT + rel * (EMB * EMB) + lg * 8;
    const unsigned short* Fb = Fbf + (long)b * (NN * EMB) + lg * 8;

    f32x4 acc[4][4];
#pragma unroll
    for (int i = 0; i < 4; ++i)
#pragma unroll
        for (int j = 0; j < 4; ++j) acc[i][j] = (f32x4){0.f, 0.f, 0.f, 0.f};

    s16x8 afr[2][4], bfr[2][4];
    // preload kk=0
#pragma unroll
    for (int hi = 0; hi < 4; ++hi)
        afr[0][hi] = *(const s16x8*)(wt + (h0 + hi * 16 + lr) * EMB);
#pragma unroll
    for (int bi = 0; bi < 4; ++bi)
        bfr[0][bi] = *(const s16x8*)(Fb + (m0 + bi * 16 + lr) * EMB);

#pragma unroll
    for (int kk = 0; kk < 8; ++kk) {
        int cur = kk & 1, nxt = cur ^ 1;
        if (kk < 7) {
            int ko = (kk + 1) * 32;
#pragma unroll
            for (int hi = 0; hi < 4; ++hi)
                afr[nxt][hi] = *(const s16x8*)(wt + (h0 + hi * 16 + lr) * EMB + ko);
#pragma unroll
            for (int bi = 0; bi < 4; ++bi)
                bfr[nxt][bi] = *(const s16x8*)(Fb + (m0 + bi * 16 + lr) * EMB + ko);
        }
#pragma unroll
        for (int hi = 0; hi < 4; ++hi)
#pragma unroll
            for (int bi = 0; bi < 4; ++bi)
                acc[hi][bi] = __builtin_amdgcn_mfma_f32_16x16x32_bf16(
                    afr[cur][hi], bfr[cur][bi], acc[hi][bi], 0, 0, 0);
    }

    // Epilogue: D rows = h, cols = m.  C layout: col = lane&15, row = (lane>>4)*4+j
#pragma unroll
    for (int hi = 0; hi < 4; ++hi) {
#pragma unroll
        for (int bi = 0; bi < 4; ++bi) {
            int m  = m0 + bi * 16 + lr;
            int kg = m >> 3, ko = m & 7;
#pragma unroll
            for (int j = 0; j < 4; ++j) {
                int h = h0 + hi * 16 + lg * 4 + j;
                if (rel < NREL)
                    FW[(long)((b * 16 + rel) * 64 + kg) * 2048 + h * 8 + ko] =
                        f2bf_bits(acc[hi][bi][j]);
                else
                    F2b[((long)b * NN + m) * EMB + h] = f2bf_bits(acc[hi][bi][j]);
            }
        }
    }
}

// ---------------------------------------------------------------------------
// K2: part[rg][b][n][h] (bf16) = adj[b][rg] @ FW[b][rg]   (one rel per block)
//   grid 512 = 8b (XCD-pinned) x 4nt(128 rows) x 16rg(1 rel), 2 blocks/CU
//   block 512 thr = 8 waves = 4 wr(32-row groups) x 2 hh(128-col halves)
//   Wave: 32 rows x 128 cols, acc[2][8] = 64 AGPR; arch ~50 -> unified ~115
//   <= 128 -> 4 waves/SIMD -> TWO co-resident blocks (barrier overlap, m114).
//   r16 pipeline discipline verbatim: reg-staged FW slice (16KB, 32B/thread,
//   conflict-free ds_write), double-buffered; adjacency dist-1 reg prefetch;
//   lgkmcnt(0)+sched_barrier+raw s_barrier; NO vmcnt(0) in loop.
//   Each wave owns its 32x128 tile -> direct bf16 store, no cross-wave reduce.
// ---------------------------------------------------------------------------
__global__ __launch_bounds__(512, 4) void k2_main(
        const float* __restrict__ adj, const unsigned short* __restrict__ FW,
        unsigned short* __restrict__ part) {
    __shared__ unsigned short Blds[2][8192];   // 2 x 16KB slice dbuf
    int bid = blockIdx.x;
    int b   = bid & 7;
    int t   = bid >> 3;          // 0..63
    int nt  = t & 3;             // 128-row tile
    int rg  = t >> 2;            // 0..15 = rel
    int tid = threadIdx.x;
    int w   = tid >> 6;          // 0..7
    int l   = tid & 63;
    int lg  = l >> 4, lr = l & 15;
    int wr  = w >> 1;            // 0..3 : 32-row group
    int hh  = w & 1;             // 0..1 : 128-col half

    int nrow0 = nt * 128 + wr * 32;   // wave's 32 output rows
    int h0    = hh * 128;             // wave's 128 output cols

    f32x4 acc[2][8];
#pragma unroll
    for (int ar = 0; ar < 2; ++ar)
#pragma unroll
        for (int f = 0; f < 8; ++f) acc[ar][f] = (f32x4){0.f, 0.f, 0.f, 0.f};

    // adjacency: row-group ar rows = nrow0 + ar*16 + lr, 32-float chunk at lg*8
    const float* adjb0 =
        adj + (((long)(b * 16 + rg)) * NN + nrow0 + lr) * NN + lg * 8;
    const float* adjb1 = adjb0 + 16 * NN;
    const unsigned short* fwb = FW + (long)(b * 16 + rg) * 131072;

    s16x8 fwr[2];                      // one slice in flight (32B/thread)
    f32x4 ax[2][2], ay[2][2];          // [slot][row-group]

    // ---- prologue: slice0 -> regs -> LDS buf0; adj slice0; slice1 -> regs
    {
        const unsigned short* s = fwb + tid * 16;
        fwr[0] = *(const s16x8*)(s);
        fwr[1] = *(const s16x8*)(s + 8);
        *(s16x8*)(&Blds[0][tid * 16])     = fwr[0];
        *(s16x8*)(&Blds[0][tid * 16 + 8]) = fwr[1];
    }
    ax[0][0] = *(const f32x4*)(adjb0); ay[0][0] = *(const f32x4*)(adjb0 + 4);
    ax[0][1] = *(const f32x4*)(adjb1); ay[0][1] = *(const f32x4*)(adjb1 + 4);
    {
        const unsigned short* s = fwb + 8192 + tid * 16;
        fwr[0] = *(const s16x8*)(s);
        fwr[1] = *(const s16x8*)(s + 8);
    }
    asm volatile("s_waitcnt lgkmcnt(0)" ::: "memory");
    __builtin_amdgcn_sched_barrier(0);
    __builtin_amdgcn_s_barrier();
    asm volatile("" ::: "memory");

#pragma unroll
    for (int s = 0; s < 16; ++s) {
        // 1. adjacency prefetch slice s+1 into the other slot (dist-1)
        if (s + 1 < 16) {
            long ao = (s + 1) * 32;
            const float* p0 = adjb0 + ao;
            const float* p1 = adjb1 + ao;
            ax[(s + 1) & 1][0] = *(const f32x4*)p0;
            ay[(s + 1) & 1][0] = *(const f32x4*)(p0 + 4);
            ax[(s + 1) & 1][1] = *(const f32x4*)p1;
            ay[(s + 1) & 1][1] = *(const f32x4*)(p1 + 4);
        }

        // 2. compute slice s: convert adj -> 2 A-frags; B from Blds[s&1]
        f32x4 x00 = ax[s & 1][0], x01 = ay[s & 1][0];
        f32x4 x10 = ax[s & 1][1], x11 = ay[s & 1][1];
        s16x8 a0, a1;
        a0[0] = (short)f2bf_hw(x00[0]); a0[1] = (short)f2bf_hw(x00[1]);
        a0[2] = (short)f2bf_hw(x00[2]); a0[3] = (short)f2bf_hw(x00[3]);
        a0[4] = (short)f2bf_hw(x01[0]); a0[5] = (short)f2bf_hw(x01[1]);
        a0[6] = (short)f2bf_hw(x01[2]); a0[7] = (short)f2bf_hw(x01[3]);
        a1[0] = (short)f2bf_hw(x10[0]); a1[1] = (short)f2bf_hw(x10[1]);
        a1[2] = (short)f2bf_hw(x10[2]); a1[3] = (short)f2bf_hw(x10[3]);
        a1[4] = (short)f2bf_hw(x11[0]); a1[5] = (short)f2bf_hw(x11[1]);
        a1[6] = (short)f2bf_hw(x11[2]); a1[7] = (short)f2bf_hw(x11[3]);

        const unsigned short* bl = &Blds[s & 1][lg * 2048 + hh * 1024];
#pragma unroll
        for (int f = 0; f < 8; ++f) {
            s16x8 bf = *(const s16x8*)(bl + f * 128 + lr * 8);
            acc[0][f] = __builtin_amdgcn_mfma_f32_16x16x32_bf16(a0, bf, acc[0][f], 0, 0, 0);
            acc[1][f] = __builtin_amdgcn_mfma_f32_16x16x32_bf16(a1, bf, acc[1][f], 0, 0, 0);
        }
        asm volatile("" ::: "memory");   // ds_reads above, ds_writes below

        // 3. ds_write slice s+1; load slice s+2 regs; lgkm-only barrier
        if (s + 1 < 16) {
            unsigned short* dst = &Blds[(s + 1) & 1][tid * 16];
            *(s16x8*)(dst)     = fwr[0];
            *(s16x8*)(dst + 8) = fwr[1];
            if (s + 2 < 16) {
                const unsigned short* sp = fwb + (long)(s + 2) * 8192 + tid * 16;
                fwr[0] = *(const s16x8*)(sp);
                fwr[1] = *(const s16x8*)(sp + 8);
            }
            asm volatile("s_waitcnt lgkmcnt(0)" ::: "memory");
            __builtin_amdgcn_sched_barrier(0);
            __builtin_amdgcn_s_barrier();
            asm volatile("" ::: "memory");
        }
    }

    // ---- direct bf16 store (each wave owns its 32x128 tile)
    unsigned short* pp = part + ((long)rg * BS + b) * (NN * EMB);
#pragma unroll
    for (int ar = 0; ar < 2; ++ar) {
#pragma unroll
        for (int f = 0; f < 8; ++f) {
            int h = h0 + f * 16 + lr;
#pragma unroll
            for (int j = 0; j < 4; ++j) {
                int n = nrow0 + ar * 16 + lg * 4 + j;
                pp[(long)n * EMB + h] = f2bf_bits(acc[ar][f][j]);
            }
        }
    }
}

// ---------------------------------------------------------------------------
// K3: out = relu(sum over 16 bf16 part slices + F2b), 8 elems/thread
// ---------------------------------------------------------------------------
__global__ __launch_bounds__(256) void k3_reduce(
        const unsigned short* __restrict__ part,
        const unsigned short* __restrict__ F2b, float* __restrict__ out) {
    const long PS = (long)BS * NN * EMB;   // elements per rg slice
    long i = ((long)blockIdx.x * 256 + threadIdx.x) * 8;
    float s[8];
    {
        s16x8 v = *(const s16x8*)(F2b + i);
#pragma unroll
        for (int j = 0; j < 8; ++j) s[j] = bf2f((unsigned short)v[j]);
    }
#pragma unroll
    for (int rg = 0; rg < 16; ++rg) {
        s16x8 v = *(const s16x8*)(part + (long)rg * PS + i);
#pragma unroll
        for (int j = 0; j < 8; ++j) s[j] += bf2f((unsigned short)v[j]);
    }
    f32x4 r0, r1;
#pragma unroll
    for (int j = 0; j < 4; ++j) {
        r0[j] = s[j] > 0.f ? s[j] : 0.f;
        r1[j] = s[j + 4] > 0.f ? s[j + 4] : 0.f;
    }
    *(f32x4*)(out + i) = r0;
    *(f32x4*)(out + i + 4) = r1;
}

// ---------------------------------------------------------------------------
extern "C" void kernel_launch(void* const* d_in, const int* in_sizes, int n_in,
                              void* d_out, int out_size, void* d_ws, size_t ws_size,
                              hipStream_t stream) {
    const float* F   = (const float*)d_in[0];   // [8][512][256]
    const float* adj = (const float*)d_in[1];   // [8][16][512][512]
    const float* Wr  = (const float*)d_in[2];   // [16][256][256]
    const float* W0  = (const float*)d_in[3];   // [256][256]
    float* out = (float*)d_out;                 // [8][512][256]

    unsigned short* wT   = (unsigned short*)d_ws;            // 17*256*256 bf16
    unsigned short* Fbf  = wT + 17 * 256 * 256;              // 8*512*256 bf16
    unsigned short* FW   = Fbf + (long)8 * 512 * 256;        // 8*16*64*2048 bf16
    unsigned short* F2b  = FW + (long)8 * 16 * 64 * 2048;    // 8*512*256 bf16
    unsigned short* part = F2b + (long)8 * 512 * 256;        // 16 slices bf16

    k0_prep<<<1600, 256, 0, stream>>>(Wr, W0, F, wT, Fbf);
    k1_fw<<<1088, 256, 0, stream>>>(Fbf, wT, FW, F2b);
    k2_main<<<512, 512, 0, stream>>>(adj, FW, part);
    k3_reduce<<<512, 256, 0, stream>>>(part, F2b, out);
}

// Round 19
// 94.992 us; speedup vs baseline: 1.2399x; 1.1316x over previous
//
#include <hip/hip_runtime.h>
#include <hip/hip_bf16.h>

#define BS   8
#define NREL 16
#define NN   512
#define EMB  256

typedef float f32x4 __attribute__((ext_vector_type(4)));
typedef short s16x4 __attribute__((ext_vector_type(4)));
typedef short s16x8 __attribute__((ext_vector_type(8)));

// f32 -> bf16 bits, round-to-nearest-even
__device__ __forceinline__ unsigned short f2bf_bits(float f) {
    union { float f; unsigned u; } v; v.f = f;
    unsigned r = (v.u + 0x7FFFu + ((v.u >> 16) & 1u)) >> 16;
    return (unsigned short)r;
}

__device__ __forceinline__ float bf2f(unsigned short u) {
    union { unsigned u; float f; } v; v.u = ((unsigned)u) << 16;
    return v.f;
}

// hw cvt path (compiler emits v_cvt_pk_bf16_f32 when paired)
__device__ __forceinline__ unsigned short f2bf_hw(float f) {
    union { __hip_bfloat16 h; unsigned short u; } v;
    v.h = __float2bfloat16(f);
    return v.u;
}

// ---------------------------------------------------------------------------
// K0: fused prep.  bid < 1088: transpose W_r + W_0 -> wT[17][h][d] bf16.
//     bid >= 1088: convert F f32 -> Fbf bf16 (512 blocks x 2048 elems).
// ---------------------------------------------------------------------------
__global__ __launch_bounds__(256) void k0_prep(
        const float* __restrict__ Wr, const float* __restrict__ W0,
        const float* __restrict__ F,
        unsigned short* __restrict__ wT, unsigned short* __restrict__ Fbf) {
    int bid = blockIdx.x;
    if (bid < 1088) {
        __shared__ float tile[32][33];
        int rel = bid / 64;          // 0..16
        int t   = bid % 64;
        int d0  = (t & 7) * 32;
        int h0  = (t >> 3) * 32;
        int tx  = threadIdx.x & 31;
        int ty  = threadIdx.x >> 5;  // 0..7
        const float* src = (rel < NREL) ? (Wr + rel * (EMB * EMB)) : W0;
#pragma unroll
        for (int k = 0; k < 4; ++k) {
            int d = d0 + ty + k * 8;
            tile[ty + k * 8][tx] = src[d * EMB + h0 + tx];
        }
        __syncthreads();
#pragma unroll
        for (int k = 0; k < 4; ++k) {
            int h = h0 + ty + k * 8;
            wT[(rel * EMB + h) * EMB + d0 + tx] = f2bf_bits(tile[tx][ty + k * 8]);
        }
    } else {
        long i = ((long)(bid - 1088) * 256 + threadIdx.x) * 8;
        f32x4 x0 = *(const f32x4*)(F + i);
        f32x4 x1 = *(const f32x4*)(F + i + 4);
        s16x8 v;
        v[0] = (short)f2bf_bits(x0[0]); v[1] = (short)f2bf_bits(x0[1]);
        v[2] = (short)f2bf_bits(x0[2]); v[3] = (short)f2bf_bits(x0[3]);
        v[4] = (short)f2bf_bits(x1[0]); v[5] = (short)f2bf_bits(x1[1]);
        v[6] = (short)f2bf_bits(x1[2]); v[7] = (short)f2bf_bits(x1[3]);
        *(s16x8*)(Fbf + i) = v;
    }
}

// ---------------------------------------------------------------------------
// K1: FW[b][rel][m][h] = sum_d F[b][m][d] * W[rel][d][h]
//   D[h][m] = wT(A) x Fbf(B), MFMA 16x16x32 bf16; distance-1 fragment dbuf.
//   rel<16  -> FW fragment-major: [(b*16+rel)*64 + m/8][h][m%8] bf16
//   rel==16 -> F2b bf16 row-major [b][n][h]
// ---------------------------------------------------------------------------
__global__ __launch_bounds__(256) void k1_fw(
        const unsigned short* __restrict__ Fbf, const unsigned short* __restrict__ wT,
        unsigned short* __restrict__ FW, unsigned short* __restrict__ F2b) {
    int bid = blockIdx.x;
    int b   = bid & 7;
    int q   = bid >> 3;          // 0..135
    int rel = q % 17;
    int mt  = q / 17;            // 0..7
    int tid = threadIdx.x;
    int w   = tid >> 6;          // 0..3
    int l   = tid & 63;
    int lg  = l >> 4;            // 0..3
    int lr  = l & 15;

    int h0 = w * 64;             // wave's 64 h-rows (M-dim)
    int m0 = mt * 64;            // block's 64 m-cols (N-dim)

    const unsigned short* wt = wT + rel * (EMB * EMB) + lg * 8;
    const unsigned short* Fb = Fbf + (long)b * (NN * EMB) + lg * 8;

    f32x4 acc[4][4];
#pragma unroll
    for (int i = 0; i < 4; ++i)
#pragma unroll
        for (int j = 0; j < 4; ++j) acc[i][j] = (f32x4){0.f, 0.f, 0.f, 0.f};

    s16x8 afr[2][4], bfr[2][4];
    // preload kk=0
#pragma unroll
    for (int hi = 0; hi < 4; ++hi)
        afr[0][hi] = *(const s16x8*)(wt + (h0 + hi * 16 + lr) * EMB);
#pragma unroll
    for (int bi = 0; bi < 4; ++bi)
        bfr[0][bi] = *(const s16x8*)(Fb + (m0 + bi * 16 + lr) * EMB);

#pragma unroll
    for (int kk = 0; kk < 8; ++kk) {
        int cur = kk & 1, nxt = cur ^ 1;
        if (kk < 7) {
            int ko = (kk + 1) * 32;
#pragma unroll
            for (int hi = 0; hi < 4; ++hi)
                afr[nxt][hi] = *(const s16x8*)(wt + (h0 + hi * 16 + lr) * EMB + ko);
#pragma unroll
            for (int bi = 0; bi < 4; ++bi)
                bfr[nxt][bi] = *(const s16x8*)(Fb + (m0 + bi * 16 + lr) * EMB + ko);
        }
#pragma unroll
        for (int hi = 0; hi < 4; ++hi)
#pragma unroll
            for (int bi = 0; bi < 4; ++bi)
                acc[hi][bi] = __builtin_amdgcn_mfma_f32_16x16x32_bf16(
                    afr[cur][hi], bfr[cur][bi], acc[hi][bi], 0, 0, 0);
    }

    // Epilogue: D rows = h, cols = m.  C layout: col = lane&15, row = (lane>>4)*4+j
#pragma unroll
    for (int hi = 0; hi < 4; ++hi) {
#pragma unroll
        for (int bi = 0; bi < 4; ++bi) {
            int m  = m0 + bi * 16 + lr;
            int kg = m >> 3, ko = m & 7;
#pragma unroll
            for (int j = 0; j < 4; ++j) {
                int h = h0 + hi * 16 + lg * 4 + j;
                if (rel < NREL)
                    FW[(long)((b * 16 + rel) * 64 + kg) * 2048 + h * 8 + ko] =
                        f2bf_bits(acc[hi][bi][j]);
                else
                    F2b[((long)b * NN + m) * EMB + h] = f2bf_bits(acc[hi][bi][j]);
            }
        }
    }
}

// ---------------------------------------------------------------------------
// K2: part[rg][b][n][h] (bf16) = sum_{r in rg(2 rels)} adj[b][r] @ FW[b][r]
//   grid 256 = 8b (XCD-pinned) x 4nt(128 rows) x 8rg(2 rels), 1 block/CU
//   block 512 thr = 8 waves = 4 wr(32-row groups) x 2 wc(K-slice parity).
//   Wave: 32 rows x 256 cols, acc[2][16].
//   r16 discipline + DENSE ADJACENCY STAGING: per iter the block loads its
//   32KB adjacency pair with 16-lanes-per-row mapping (256B contiguous per
//   row per instruction, 2x r16's 128B), converts f32->bf16 at stage time,
//   ds_writes into XOR-swizzled AL (byte ^= (row&7)<<4, same swizzle on
//   read -> conflict-free b128 A-frag reads).  Compute phase has ZERO cvt.
//   lgkmcnt(0)+sched_barrier+raw s_barrier per iter; no vmcnt(0) in loop.
// ---------------------------------------------------------------------------
__global__ __launch_bounds__(512, 2) void k2_main(
        const float* __restrict__ adj, const unsigned short* __restrict__ FW,
        unsigned short* __restrict__ part) {
    __shared__ unsigned short Blds[2][16384];  // FW pair dbuf (2 x 32KB)
    __shared__ unsigned short AL[2][8192];     // adjacency bf16 pair dbuf (2 x 16KB)
    int bid = blockIdx.x;
    int b   = bid & 7;
    int t   = bid >> 3;          // 0..31
    int nt  = t & 3;
    int rg  = t >> 2;            // 0..7
    int tid = threadIdx.x;
    int w   = tid >> 6;          // 0..7
    int l   = tid & 63;
    int lg  = l >> 4, lr = l & 15;
    int wr  = w >> 1;            // 0..3 : 32-row group
    int wc  = w & 1;             // 0..1 : K-slice parity

    int nrow = nt * 128 + wr * 32;    // wave's 32 output rows

    f32x4 acc0[16], acc1[16];
#pragma unroll
    for (int i = 0; i < 16; ++i) {
        acc0[i] = (f32x4){0.f, 0.f, 0.f, 0.f};
        acc1[i] = (f32x4){0.f, 0.f, 0.f, 0.f};
    }

    const unsigned short* fwb = FW + (long)(b * 16 + rg * 2) * 131072;
    // adjacency staging: thread covers rows r0s..r0s+3 (block-relative),
    // 16 floats at pos*4 within the pair's 64-float row chunk.
    int pos = tid & 15;          // 16 lanes per row -> 256B contiguous/row/inst
    int r0s = (tid >> 4) * 4;    // 4 rows per thread
    const float* adjstage =
        adj + (((long)(b * 16 + rg * 2)) * NN + nt * 128 + r0s) * NN + pos * 4;

    s16x8 fwr[4];                // FW pair in flight (64B/thread)
    f32x4 axr[4];                // adjacency raw pair in flight (4 rows x 4 f32)

#define POFF(p) ((long)((p) >> 3) * 131072 + ((p) & 7) * 16384)
#define ASRC(p) (adjstage + (long)((p) >> 3) * (NN * NN) + ((p) & 7) * 64)

    // adjacency cvt+swizzled-write of raw regs into AL[buf]
#define ASTAGE(bufidx)                                                        \
    {                                                                         \
        _Pragma("unroll")                                                     \
        for (int g = 0; g < 4; ++g) {                                         \
            s16x4 v;                                                          \
            v[0] = (short)f2bf_hw(axr[g][0]);                                 \
            v[1] = (short)f2bf_hw(axr[g][1]);                                 \
            v[2] = (short)f2bf_hw(axr[g][2]);                                 \
            v[3] = (short)f2bf_hw(axr[g][3]);                                 \
            int rl = r0s + g;                                                 \
            *(s16x4*)((char*)&AL[bufidx][0] + rl * 128 +                      \
                      ((pos * 8) ^ ((rl & 7) << 4))) = v;                     \
        }                                                                     \
    }

    // ---- prologue ----
    {   // FW pair 0: regs -> LDS buf0
        const unsigned short* s = fwb + POFF(0) + tid * 8;
#pragma unroll
        for (int c = 0; c < 4; ++c) fwr[c] = *(const s16x8*)(s + c * 4096);
#pragma unroll
        for (int c = 0; c < 4; ++c)
            *(s16x8*)(&Blds[0][c * 4096 + tid * 8]) = fwr[c];
    }
    {   // adjacency pair 0: dense load, cvt, swizzled write buf0
        const float* s = ASRC(0);
#pragma unroll
        for (int g = 0; g < 4; ++g) axr[g] = *(const f32x4*)(s + g * NN);
        ASTAGE(0);
    }
    {   // FW pair 1 regs; adjacency pair 1 raw regs
        const unsigned short* s = fwb + POFF(1) + tid * 8;
#pragma unroll
        for (int c = 0; c < 4; ++c) fwr[c] = *(const s16x8*)(s + c * 4096);
        const float* a = ASRC(1);
#pragma unroll
        for (int g = 0; g < 4; ++g) axr[g] = *(const f32x4*)(a + g * NN);
    }
    asm volatile("s_waitcnt lgkmcnt(0)" ::: "memory");
    __builtin_amdgcn_sched_barrier(0);
    __builtin_amdgcn_s_barrier();
    asm volatile("" ::: "memory");

#pragma unroll
    for (int i = 0; i < 16; ++i) {
        // 1. compute slice 2i+wc: A-frags from AL[i&1] (swizzled), B from Blds
        s16x8 a0, a1;
        {
            int rl0 = wr * 32 + lr;
            int rl1 = rl0 + 16;
            a0 = *(const s16x8*)((const char*)&AL[i & 1][0] + rl0 * 128 +
                                 ((wc * 64 + lg * 16) ^ ((rl0 & 7) << 4)));
            a1 = *(const s16x8*)((const char*)&AL[i & 1][0] + rl1 * 128 +
                                 ((wc * 64 + lg * 16) ^ ((rl1 & 7) << 4)));
        }
        const unsigned short* bl = &Blds[i & 1][wc * 8192 + lg * 2048];
#pragma unroll
        for (int f = 0; f < 16; ++f) {
            s16x8 bf = *(const s16x8*)(bl + (f * 16 + lr) * 8);
            acc0[f] = __builtin_amdgcn_mfma_f32_16x16x32_bf16(a0, bf, acc0[f], 0, 0, 0);
            acc1[f] = __builtin_amdgcn_mfma_f32_16x16x32_bf16(a1, bf, acc1[f], 0, 0, 0);
        }
        asm volatile("" ::: "memory");   // ds_reads above, ds_writes below

        // 2. stage pair i+1 (FW regs + adjacency cvt) into buf[(i+1)&1];
        //    reload both reg rings with pair i+2; lgkm-only barrier
        if (i + 1 < 16) {
            unsigned short* dst = &Blds[(i + 1) & 1][tid * 8];
#pragma unroll
            for (int c = 0; c < 4; ++c) *(s16x8*)(dst + c * 4096) = fwr[c];
            ASTAGE((i + 1) & 1);
            if (i + 2 < 16) {
                const unsigned short* s = fwb + POFF(i + 2) + tid * 8;
#pragma unroll
                for (int c = 0; c < 4; ++c) fwr[c] = *(const s16x8*)(s + c * 4096);
                const float* a = ASRC(i + 2);
#pragma unroll
                for (int g = 0; g < 4; ++g) axr[g] = *(const f32x4*)(a + g * NN);
            }
            asm volatile("s_waitcnt lgkmcnt(0)" ::: "memory");
            __builtin_amdgcn_sched_barrier(0);
            __builtin_amdgcn_s_barrier();
            asm volatile("" ::: "memory");
        }
    }
#undef POFF
#undef ASRC
#undef ASTAGE

    // ---- cross-wc reduce via LDS, 2 chunks (g = row-group), bf16 store
    float* lf = (float*)Blds;          // 16384 floats = 64KB
    unsigned short* pp = part + ((long)rg * BS + b) * (NN * EMB);
#pragma unroll
    for (int g = 0; g < 2; ++g) {
        __syncthreads();
        if (wc == 1) {
#pragma unroll
            for (int f = 0; f < 16; ++f)
#pragma unroll
                for (int j = 0; j < 4; ++j)
                    lf[wr * 4096 + (f * 4 + j) * 64 + l] =
                        g ? acc1[f][j] : acc0[f][j];
        }
        __syncthreads();
        if (wc == 0) {
#pragma unroll
            for (int f = 0; f < 16; ++f) {
                int h = f * 16 + lr;
#pragma unroll
                for (int j = 0; j < 4; ++j) {
                    int n = nrow + g * 16 + lg * 4 + j;
                    float v = (g ? acc1[f][j] : acc0[f][j]) +
                              lf[wr * 4096 + (f * 4 + j) * 64 + l];
                    pp[(long)n * EMB + h] = f2bf_bits(v);
                }
            }
        }
    }
}

// ---------------------------------------------------------------------------
// K3: out = relu(sum over 8 bf16 part slices + F2b), 8 elems/thread
// ---------------------------------------------------------------------------
__global__ __launch_bounds__(256) void k3_reduce(
        const unsigned short* __restrict__ part,
        const unsigned short* __restrict__ F2b, float* __restrict__ out) {
    const long PS = (long)BS * NN * EMB;   // elements per rg slice
    long i = ((long)blockIdx.x * 256 + threadIdx.x) * 8;
    float s[8];
    {
        s16x8 v = *(const s16x8*)(F2b + i);
#pragma unroll
        for (int j = 0; j < 8; ++j) s[j] = bf2f((unsigned short)v[j]);
    }
#pragma unroll
    for (int rg = 0; rg < 8; ++rg) {
        s16x8 v = *(const s16x8*)(part + (long)rg * PS + i);
#pragma unroll
        for (int j = 0; j < 8; ++j) s[j] += bf2f((unsigned short)v[j]);
    }
    f32x4 r0, r1;
#pragma unroll
    for (int j = 0; j < 4; ++j) {
        r0[j] = s[j] > 0.f ? s[j] : 0.f;
        r1[j] = s[j + 4] > 0.f ? s[j + 4] : 0.f;
    }
    *(f32x4*)(out + i) = r0;
    *(f32x4*)(out + i + 4) = r1;
}

// ---------------------------------------------------------------------------
extern "C" void kernel_launch(void* const* d_in, const int* in_sizes, int n_in,
                              void* d_out, int out_size, void* d_ws, size_t ws_size,
                              hipStream_t stream) {
    const float* F   = (const float*)d_in[0];   // [8][512][256]
    const float* adj = (const float*)d_in[1];   // [8][16][512][512]
    const float* Wr  = (const float*)d_in[2];   // [16][256][256]
    const float* W0  = (const float*)d_in[3];   // [256][256]
    float* out = (float*)d_out;                 // [8][512][256]

    unsigned short* wT   = (unsigned short*)d_ws;            // 17*256*256 bf16
    unsigned short* Fbf  = wT + 17 * 256 * 256;              // 8*512*256 bf16
    unsigned short* FW   = Fbf + (long)8 * 512 * 256;        // 8*16*64*2048 bf16
    unsigned short* F2b  = FW + (long)8 * 16 * 64 * 2048;    // 8*512*256 bf16
    unsigned short* part = F2b + (long)8 * 512 * 256;        // 8 slices bf16

    k0_prep<<<1600, 256, 0, stream>>>(Wr, W0, F, wT, Fbf);
    k1_fw<<<1088, 256, 0, stream>>>(Fbf, wT, FW, F2b);
    k2_main<<<256, 512, 0, stream>>>(adj, FW, part);
    k3_reduce<<<512, 256, 0, stream>>>(part, F2b, out);
}